// Round 8
// baseline (134.211 us; speedup 1.0000x reference)
//
#include <hip/hip_runtime.h>
#include <hip/hip_fp16.h>

// FactoredBlock: out[n,:] = sum_{k in row n} values[k] * weights[f_table[active_idx[k]], :]
// batch_idx sorted. Theory: global-path gather is L1-MSHR bound (~25us floor);
// weights must be read from LDS. K-sliced LDS-resident W:
//   build_a: CSR offsets + per-(row,slice) bucket counts + W f32->f16
//   build_b: per-row bucket prefix -> bstart[N*9]; cnt becomes fill counters
//   build_c: scatter pairs {f_local:16 | f16(v):16} bucketed by slice
//   gemm   : 512 blocks x 1024 thr (2/CU, 32 waves/CU). 32 rows/block; per
//            slice (8 x 96 rows): stage 48 KB W slice to LDS, each wave
//            handles 2 rows; 4 nnz per group = 2 broadcast pair reads +
//            2 ds_read_b128 (dual-nnz: lanes<32 even, >=32 odd), hfma2 acc,
//            shfl_xor(32) combine, f32 store.

#define OUT_COLS 256
#define INTER 768
#define SLICES 8
#define SROWS 96                  // INTER / SLICES
#define BROWS 32                  // rows per gemm block
#define GTHREADS 1024
#define PS_CAP 2056               // pairs LDS capacity (avg block ~1024)
#define NWEL (INTER * OUT_COLS)

__device__ __forceinline__ unsigned f16bits(float x) {
    return (unsigned)__half_as_ushort(__float2half(x));
}

// ---------------- build_a: offsets + bucket counts + W convert ----------------
__global__ __launch_bounds__(256)
void build_a(const int* __restrict__ bi, const int* __restrict__ ai,
             const int* __restrict__ ft, const float* __restrict__ w,
             int* __restrict__ offsets, unsigned* __restrict__ cnt,
             __half* __restrict__ wh, int nnz, int N)
{
    const int k = blockIdx.x * 256 + threadIdx.x;
    if (k < NWEL) wh[k] = __float2half(w[k]);
    if (k >= nnz) return;
    const int r  = bi[k];
    const int rp = (k == 0) ? -1 : bi[k - 1];
    for (int row = rp + 1; row <= r; ++row) offsets[row] = k;
    if (k == nnz - 1)
        for (int row = r + 1; row <= N; ++row) offsets[row] = nnz;
    const int f = ft[ai[k]];
    const int s = (f * 683) >> 16;            // f / 96 for f < 768
    atomicAdd(&cnt[r * 8 + s], 1u);
}

// ---------------- build_b: per-row bucket prefix ----------------
__global__ __launch_bounds__(256)
void build_b(const int* __restrict__ offsets, unsigned* __restrict__ cnt,
             int* __restrict__ bstart, int N)
{
    const int r = blockIdx.x * 256 + threadIdx.x;
    if (r >= N) return;
    int acc = offsets[r];
#pragma unroll
    for (int s = 0; s < 8; ++s) {
        bstart[r * 9 + s] = acc;
        const unsigned c = cnt[r * 8 + s];
        cnt[r * 8 + s] = (unsigned)acc;       // becomes fill counter
        acc += (int)c;
    }
    bstart[r * 9 + 8] = acc;                  // == offsets[r+1]
}

// ---------------- build_c: scatter bucketed pairs ----------------
__global__ __launch_bounds__(256)
void build_c(const int* __restrict__ bi, const int* __restrict__ ai,
             const float* __restrict__ vals, const int* __restrict__ ft,
             unsigned* __restrict__ cnt, unsigned* __restrict__ bp, int nnz)
{
    const int k = blockIdx.x * 256 + threadIdx.x;
    if (k >= nnz) return;
    const int r = bi[k];
    const int f = ft[ai[k]];
    const int s = (f * 683) >> 16;
    const int fl = f - s * SROWS;             // local row within slice, < 96
    const unsigned dst = atomicAdd(&cnt[r * 8 + s], 1u);
    bp[dst] = ((unsigned)fl << 16) | f16bits(vals[k]);
}

// ---------------- gemm: LDS-resident W slices ----------------
__global__ __launch_bounds__(GTHREADS, 8)   // 8 waves/EU -> 2 blocks/CU
void gemm_kernel(const int* __restrict__ offsets, const int* __restrict__ bstart,
                 const unsigned* __restrict__ bp, const __half* __restrict__ wh,
                 float* __restrict__ out, int N)
{
    __shared__ __align__(16) __half Ws[SROWS * OUT_COLS];   // 48 KB
    __shared__ unsigned Ps[PS_CAP];                         // 8 KB
    __shared__ int ls[BROWS * 9];                           // 1.125 KB

    const int t    = threadIdx.x;
    const int lane = t & 63;
    const int wave = t >> 6;                  // 0..15
    const int hi   = lane >> 5;               // 0: even nnz, 1: odd nnz
    const int r0   = blockIdx.x * BROWS;
    const int nrows = min(BROWS, N - r0);

    const int base = offsets[r0];
    const int tot  = offsets[r0 + nrows] - base;

    for (int i = t; i < nrows * 9; i += GTHREADS) ls[i] = bstart[r0 * 9 + i];
    const bool inlds = (tot <= PS_CAP - 8);
    if (inlds)
        for (int i = t; i < tot; i += GTHREADS) Ps[i] = bp[base + i];

    __half2 acc[2][4];
#pragma unroll
    for (int rr = 0; rr < 2; ++rr)
        acc[rr][0] = acc[rr][1] = acc[rr][2] = acc[rr][3] = __float2half2_rn(0.f);

    const int colh = (lane & 31) << 3;        // 8 f16 cols per lane

    for (int s = 0; s < SLICES; ++s) {
        // stage 48 KB slice (contiguous in wh): 3072 uint4, 3 per thread
        {
            const uint4* g  = (const uint4*)(wh + s * (SROWS * OUT_COLS));
            uint4*       sw = (uint4*)Ws;
#pragma unroll
            for (int i = 0; i < 3; ++i) sw[t + i * GTHREADS] = g[t + i * GTHREADS];
        }
        __syncthreads();

#pragma unroll
        for (int rr = 0; rr < 2; ++rr) {
            const int r = wave * 2 + rr;
            if (r < nrows) {
                const int js = ls[r * 9 + s] - base;
                const int je = ls[r * 9 + s + 1] - base;
                for (int j = js; j < je; j += 4) {
                    const int iA = j + 2 * hi;          // lo: j,   hi: j+2
                    const int iB = iA + 1;              // lo: j+1, hi: j+3
                    unsigned pA, pB;
                    if (inlds) { pA = Ps[iA]; pB = Ps[iB]; }
                    else       { pA = bp[base + iA]; pB = bp[base + iB]; }
                    pA = (iA < je) ? pA : 0u;
                    pB = (iB < je) ? pB : 0u;
                    const uint4 wA = *(const uint4*)&Ws[(pA >> 16) * OUT_COLS + colh];
                    const uint4 wB = *(const uint4*)&Ws[(pB >> 16) * OUT_COLS + colh];
                    unsigned va = (pA & 0xffffu) | (pA << 16);
                    unsigned vb = (pB & 0xffffu) | (pB << 16);
                    const __half2 hva = *(const __half2*)&va;
                    const __half2 hvb = *(const __half2*)&vb;
                    const __half2* wa2 = (const __half2*)&wA;
                    const __half2* wb2 = (const __half2*)&wB;
                    acc[rr][0] = __hfma2(wa2[0], hva, acc[rr][0]);
                    acc[rr][1] = __hfma2(wa2[1], hva, acc[rr][1]);
                    acc[rr][2] = __hfma2(wa2[2], hva, acc[rr][2]);
                    acc[rr][3] = __hfma2(wa2[3], hva, acc[rr][3]);
                    acc[rr][0] = __hfma2(wb2[0], hvb, acc[rr][0]);
                    acc[rr][1] = __hfma2(wb2[1], hvb, acc[rr][1]);
                    acc[rr][2] = __hfma2(wb2[2], hvb, acc[rr][2]);
                    acc[rr][3] = __hfma2(wb2[3], hvb, acc[rr][3]);
                }
            }
        }
        __syncthreads();
    }

#pragma unroll
    for (int rr = 0; rr < 2; ++rr) {
        const int r = wave * 2 + rr;
        if (r >= nrows) continue;
        __half2 a0 = acc[rr][0], a1 = acc[rr][1], a2 = acc[rr][2], a3 = acc[rr][3];
        const int b0 = __shfl_xor(*(const int*)&a0, 32);
        const int b1 = __shfl_xor(*(const int*)&a1, 32);
        const int b2 = __shfl_xor(*(const int*)&a2, 32);
        const int b3 = __shfl_xor(*(const int*)&a3, 32);
        a0 = __hadd2(a0, *(const __half2*)&b0);
        a1 = __hadd2(a1, *(const __half2*)&b1);
        a2 = __hadd2(a2, *(const __half2*)&b2);
        a3 = __hadd2(a3, *(const __half2*)&b3);
        if (hi == 0) {
            float4 o0, o1;
            o0.x = __low2float(a0); o0.y = __high2float(a0);
            o0.z = __low2float(a1); o0.w = __high2float(a1);
            o1.x = __low2float(a2); o1.y = __high2float(a2);
            o1.z = __low2float(a3); o1.w = __high2float(a3);
            float* orow = out + (size_t)(r0 + r) * OUT_COLS + ((lane & 31) << 3);
            *(float4*)orow = o0;
            *(float4*)(orow + 4) = o1;
        }
    }
}

// ---------------- fallback (binary search, f32 weights), if ws too small ----------------
__global__ __launch_bounds__(256, 8)
void fallback_kernel(const int* __restrict__ batch_idx,
                     const int* __restrict__ active_idx,
                     const float* __restrict__ values,
                     const int* __restrict__ f_table,
                     const float* __restrict__ weights,
                     float* __restrict__ out,
                     int nnz, int N)
{
    const int wave = threadIdx.x >> 6;
    const int lane = threadIdx.x & 63;
    const int row  = blockIdx.x * 4 + wave;
    if (row >= N) return;

    int lo1 = 0, hi1 = nnz, lo2 = 0, hi2 = nnz;
    while ((lo1 < hi1) | (lo2 < hi2)) {
        if (lo1 < hi1) { int m = (lo1 + hi1) >> 1; if (batch_idx[m] < row) lo1 = m + 1; else hi1 = m; }
        if (lo2 < hi2) { int m = (lo2 + hi2) >> 1; if (batch_idx[m] < row + 1) lo2 = m + 1; else hi2 = m; }
    }
    float4 acc = make_float4(0.f, 0.f, 0.f, 0.f);
    const float* __restrict__ wcol = weights + (lane << 2);
    for (int b = lo1; b < lo2; b += 64) {
        const int c = min(lo2 - b, 64);
        float v_l = 0.f; int f_l = 0;
        if (lane < c) { const int k = b + lane; v_l = values[k]; f_l = f_table[active_idx[k]]; }
        for (int j = 0; j < c; ++j) {
            const float v = __shfl(v_l, j);
            const int   f = __shfl(f_l, j);
            const float4 w = *(const float4*)(wcol + f * OUT_COLS);
            acc.x = fmaf(v, w.x, acc.x);
            acc.y = fmaf(v, w.y, acc.y);
            acc.z = fmaf(v, w.z, acc.z);
            acc.w = fmaf(v, w.w, acc.w);
        }
    }
    *(float4*)(out + row * OUT_COLS + (lane << 2)) = acc;
}

extern "C" void kernel_launch(void* const* d_in, const int* in_sizes, int n_in,
                              void* d_out, int out_size, void* d_ws, size_t ws_size,
                              hipStream_t stream) {
    const int*   batch_idx  = (const int*)d_in[0];
    const int*   active_idx = (const int*)d_in[1];
    const float* values     = (const float*)d_in[2];
    const int*   f_table    = (const int*)d_in[3];
    const float* weights    = (const float*)d_in[4];
    float*       out        = (float*)d_out;

    const int nnz = in_sizes[0];
    const int N   = out_size / OUT_COLS;      // 16384

    // ws layout (16 B aligned): offsets[N+1] | cnt[N*8] | bstart[N*9] |
    //                           wh[NWEL] f16 | bp[nnz] | slack
    const size_t a16 = 15;
    const size_t cnt_off    = (((size_t)(N + 1) * 4) + a16) & ~a16;
    const size_t bstart_off = (cnt_off + (size_t)N * 8 * 4 + a16) & ~a16;
    const size_t wh_off     = (bstart_off + (size_t)N * 9 * 4 + a16) & ~a16;
    const size_t bp_off     = (wh_off + (size_t)NWEL * 2 + a16) & ~a16;
    const size_t need       = bp_off + (size_t)nnz * 4 + 256;

    if (ws_size >= need) {
        int*      offsets = (int*)d_ws;
        unsigned* cnt     = (unsigned*)((char*)d_ws + cnt_off);
        int*      bstart  = (int*)((char*)d_ws + bstart_off);
        __half*   wh      = (__half*)((char*)d_ws + wh_off);
        unsigned* bp      = (unsigned*)((char*)d_ws + bp_off);

        hipMemsetAsync(cnt, 0, (size_t)N * 8 * 4, stream);

        const int work_a = (nnz > NWEL) ? nnz : NWEL;
        build_a<<<(work_a + 255) / 256, 256, 0, stream>>>(
            batch_idx, active_idx, f_table, weights, offsets, cnt, wh, nnz, N);
        build_b<<<(N + 255) / 256, 256, 0, stream>>>(offsets, cnt, bstart, N);
        build_c<<<(nnz + 255) / 256, 256, 0, stream>>>(
            batch_idx, active_idx, values, f_table, cnt, bp, nnz);
        gemm_kernel<<<(N + BROWS - 1) / BROWS, GTHREADS, 0, stream>>>(
            offsets, bstart, bp, wh, out, N);
    } else {
        fallback_kernel<<<(N + 3) / 4, 256, 0, stream>>>(
            batch_idx, active_idx, values, f_table, weights, out, nnz, N);
    }
}

// Round 9
// 105.744 us; speedup vs baseline: 1.2692x; 1.2692x over previous
//
#include <hip/hip_runtime.h>

// FactoredBlock: out[n,:] = sum_{k in row n} values[k] * weights[f_table[active_idx[k]], :]
// batch_idx sorted. Gather-style kernels are L1-miss-concurrency bound (~25us
// floor, rounds 2-8). Exit: densify to bf16 A [N,768] then dense MFMA GEMM
// A[N,768] x W[768,256] (6.4 GFLOP bf16 ~ 10us-class).
//   build_a : CSR offsets[N+1] + W f32 -> bf16 transposed BT[256][768]
//   densify : 1 wave/row; scatter-add (f,v) into 768-f32 LDS row (dup-safe),
//             convert+store bf16 A row (fully overwrites A)
//   mfma_gemm: BM=64 BN=128 BK=32, grid (M/64, 2), 256 thr (4 waves),
//             pipelined global->reg->LDS staging, 16x16x32 bf16 MFMA.
//             Layouts (m89/m120-verified): A-frag m=lane&15,k=quad*8+j;
//             B-frag n=lane&15,k=quad*8+j; C/D col=lane&15,row=quad*4+reg.

#define OUT_COLS 256
#define INTER 768
#define NWEL (INTER * OUT_COLS)
#define BM 64
#define BN 128
#define BK 32
#define LSTRIDE 40   // ushort stride: 80 B, 16-aligned, <=2-way bank alias (free)

typedef __attribute__((ext_vector_type(8))) short short8;
typedef __attribute__((ext_vector_type(4))) float floatx4;

__device__ __forceinline__ unsigned short f2bf(float x) {   // RTN-even
    unsigned u = __float_as_uint(x);
    return (unsigned short)((u + 0x7fffu + ((u >> 16) & 1u)) >> 16);
}

// ---------------- build_a: offsets + W -> bf16 transposed ----------------
__global__ __launch_bounds__(256)
void build_a(const int* __restrict__ bi, const float* __restrict__ w,
             int* __restrict__ offsets, unsigned short* __restrict__ BT,
             int nnz, int N)
{
    const int k = blockIdx.x * 256 + threadIdx.x;
    if (k < NWEL) {
        const int f = k >> 8, c = k & 255;       // w[f][c]
        BT[c * INTER + f] = f2bf(w[k]);          // BT[n][k] k-contiguous
    }
    if (k >= nnz) return;
    const int r  = bi[k];
    const int rp = (k == 0) ? -1 : bi[k - 1];
    for (int row = rp + 1; row <= r; ++row) offsets[row] = k;
    if (k == nnz - 1)
        for (int row = r + 1; row <= N; ++row) offsets[row] = nnz;
}

// ---------------- densify: sparse row -> dense bf16 row ----------------
__global__ __launch_bounds__(256)
void densify(const int* __restrict__ offsets, const int* __restrict__ ai,
             const float* __restrict__ vals, const int* __restrict__ ft,
             unsigned short* __restrict__ A, int N)
{
    __shared__ float xs[4 * INTER];              // 12 KB, one 768-row per wave
    const int lane = threadIdx.x & 63;
    const int wave = threadIdx.x >> 6;
    const int r = blockIdx.x * 4 + wave;
    if (r >= N) return;
    float* x = xs + wave * INTER;

#pragma unroll
    for (int i = 0; i < 3; ++i)                  // zero 768 f32 (b128 writes)
        *(float4*)(x + i * 256 + (lane << 2)) = make_float4(0.f, 0.f, 0.f, 0.f);

    const int start = offsets[r], end = offsets[r + 1];
    for (int kb = start; kb < end; kb += 64) {
        const int idx = kb + lane;
        if (idx < end) {
            const int f = ft[ai[idx]];
            atomicAdd(&x[f], vals[idx]);         // ds_add_f32; dup-f safe
        }
    }

    unsigned short* arow = A + (size_t)r * INTER;
#pragma unroll
    for (int i = 0; i < 3; ++i) {
        const float4 v = *(const float4*)(x + i * 256 + (lane << 2));
        ushort4 h;
        h.x = f2bf(v.x); h.y = f2bf(v.y); h.z = f2bf(v.z); h.w = f2bf(v.w);
        *(ushort4*)(arow + i * 256 + (lane << 2)) = h;   // 512 B/instr coalesced
    }
}

// ---------------- mfma_gemm: C[N,256] = A[N,768] x BT^T ----------------
__global__ __launch_bounds__(256)
void mfma_gemm(const unsigned short* __restrict__ A,
               const unsigned short* __restrict__ BT,
               float* __restrict__ out, int N)
{
    __shared__ __align__(16) unsigned short As[BM * LSTRIDE];   // 5 KB
    __shared__ __align__(16) unsigned short Bs[BN * LSTRIDE];   // 10 KB

    const int t    = threadIdx.x;
    const int lane = t & 63;
    const int wave = t >> 6;                     // 0..3
    const int quad = lane >> 4, l16 = lane & 15;
    const int m0 = blockIdx.x * BM;
    const int n1 = blockIdx.y * BN;

    floatx4 acc[8];
#pragma unroll
    for (int i = 0; i < 8; ++i) acc[i] = (floatx4){0.f, 0.f, 0.f, 0.f};

    // staging assignment: A: 64 rows x 4 segs of 8 ushort; B: 128 n x 2 halves of 16 ushort
    const int arow = t >> 2, aseg = t & 3;
    const int bn = t & 127, bhalf = t >> 7;
    const int arow_c = min(m0 + arow, N - 1);    // clamp (harmless dup read)
    const unsigned short* Asrc = A + (size_t)arow_c * INTER + aseg * 8;
    const unsigned short* Bsrc = BT + (size_t)(n1 + bn) * INTER + bhalf * 16;
    unsigned short* Adst = As + arow * LSTRIDE + aseg * 8;
    unsigned short* Bdst = Bs + bn * LSTRIDE + bhalf * 16;
    const unsigned short* aread = As + (wave * 16 + l16) * LSTRIDE + quad * 8;

    uint4 apre  = *(const uint4*)(Asrc);
    uint4 bpre0 = *(const uint4*)(Bsrc);
    uint4 bpre1 = *(const uint4*)(Bsrc + 8);

    for (int kc = 0; kc < INTER; kc += BK) {
        *(uint4*)Adst       = apre;
        *(uint4*)Bdst       = bpre0;
        *(uint4*)(Bdst + 8) = bpre1;
        __syncthreads();
        if (kc + BK < INTER) {                   // prefetch next step
            apre  = *(const uint4*)(Asrc + kc + BK);
            bpre0 = *(const uint4*)(Bsrc + kc + BK);
            bpre1 = *(const uint4*)(Bsrc + kc + BK + 8);
        }
        const short8 af = *(const short8*)aread;
#pragma unroll
        for (int tn = 0; tn < 8; ++tn) {
            const short8 bf = *(const short8*)(Bs + (tn * 16 + l16) * LSTRIDE + quad * 8);
            acc[tn] = __builtin_amdgcn_mfma_f32_16x16x32_bf16(af, bf, acc[tn], 0, 0, 0);
        }
        __syncthreads();
    }

#pragma unroll
    for (int tn = 0; tn < 8; ++tn) {
#pragma unroll
        for (int reg = 0; reg < 4; ++reg) {
            const int row = m0 + wave * 16 + quad * 4 + reg;
            const int col = n1 + tn * 16 + l16;
            if (row < N) out[(size_t)row * OUT_COLS + col] = acc[tn][reg];
        }
    }
}

// ---------------- fallback (binary search, f32 weights), if ws too small ----------------
__global__ __launch_bounds__(256, 8)
void fallback_kernel(const int* __restrict__ batch_idx,
                     const int* __restrict__ active_idx,
                     const float* __restrict__ values,
                     const int* __restrict__ f_table,
                     const float* __restrict__ weights,
                     float* __restrict__ out,
                     int nnz, int N)
{
    const int wave = threadIdx.x >> 6;
    const int lane = threadIdx.x & 63;
    const int row  = blockIdx.x * 4 + wave;
    if (row >= N) return;

    int lo1 = 0, hi1 = nnz, lo2 = 0, hi2 = nnz;
    while ((lo1 < hi1) | (lo2 < hi2)) {
        if (lo1 < hi1) { int m = (lo1 + hi1) >> 1; if (batch_idx[m] < row) lo1 = m + 1; else hi1 = m; }
        if (lo2 < hi2) { int m = (lo2 + hi2) >> 1; if (batch_idx[m] < row + 1) lo2 = m + 1; else hi2 = m; }
    }
    float4 acc = make_float4(0.f, 0.f, 0.f, 0.f);
    const float* __restrict__ wcol = weights + (lane << 2);
    for (int b = lo1; b < lo2; b += 64) {
        const int c = min(lo2 - b, 64);
        float v_l = 0.f; int f_l = 0;
        if (lane < c) { const int k = b + lane; v_l = values[k]; f_l = f_table[active_idx[k]]; }
        for (int j = 0; j < c; ++j) {
            const float v = __shfl(v_l, j);
            const int   f = __shfl(f_l, j);
            const float4 w = *(const float4*)(wcol + f * OUT_COLS);
            acc.x = fmaf(v, w.x, acc.x);
            acc.y = fmaf(v, w.y, acc.y);
            acc.z = fmaf(v, w.z, acc.z);
            acc.w = fmaf(v, w.w, acc.w);
        }
    }
    *(float4*)(out + row * OUT_COLS + (lane << 2)) = acc;
}

extern "C" void kernel_launch(void* const* d_in, const int* in_sizes, int n_in,
                              void* d_out, int out_size, void* d_ws, size_t ws_size,
                              hipStream_t stream) {
    const int*   batch_idx  = (const int*)d_in[0];
    const int*   active_idx = (const int*)d_in[1];
    const float* values     = (const float*)d_in[2];
    const int*   f_table    = (const int*)d_in[3];
    const float* weights    = (const float*)d_in[4];
    float*       out        = (float*)d_out;

    const int nnz = in_sizes[0];
    const int N   = out_size / OUT_COLS;         // 16384

    // ws layout (16 B aligned): offsets[N+1] | BT[256*768] bf16 | A[N*768] bf16
    const size_t a16    = 15;
    const size_t bt_off = (((size_t)(N + 1) * 4) + a16) & ~a16;
    const size_t a_off  = (bt_off + (size_t)NWEL * 2 + a16) & ~a16;
    const size_t need   = a_off + (size_t)N * INTER * 2 + 256;

    if (ws_size >= need) {
        int*            offsets = (int*)d_ws;
        unsigned short* BT      = (unsigned short*)((char*)d_ws + bt_off);
        unsigned short* A       = (unsigned short*)((char*)d_ws + a_off);

        const int work = (nnz > NWEL) ? nnz : NWEL;
        build_a<<<(work + 255) / 256, 256, 0, stream>>>(batch_idx, weights, offsets, BT, nnz, N);
        densify<<<(N + 3) / 4, 256, 0, stream>>>(offsets, active_idx, values, f_table, A, N);
        dim3 grid((N + BM - 1) / BM, OUT_COLS / BN);
        mfma_gemm<<<grid, 256, 0, stream>>>(A, BT, out, N);
    } else {
        fallback_kernel<<<(N + 3) / 4, 256, 0, stream>>>(
            batch_idx, active_idx, values, f_table, weights, out, nnz, N);
    }
}

// Round 10
// 92.266 us; speedup vs baseline: 1.4546x; 1.1461x over previous
//
#include <hip/hip_runtime.h>
#include <hip/hip_fp16.h>

// FactoredBlock: out[n,:] = sum_{k in row n} values[k] * weights[f_table[active_idx[k]], :]
// batch_idx sorted. Two dispatches (r7 shape):
//   build_kernel: fused (weights f32->f16) + CSR offsets[N+1] + packed pairs
//                 u32 {f:16 | f16bits(v):16}
//   gemm_kernel : 1 wave/row, dual-nnz 16 B/lane weight loads, hfma2.
//                 R10 change: bitonic-sort the wave's 64 pairs by f before
//                 processing. Co-resident waves then sweep f-space together
//                 -> L1 working set ~ narrow f-band -> line misses drop from
//                 ~15k/CU (8% hit, random) toward ~6144/CU (each line once).

#define OUT_COLS 256
#define WAVES_PER_BLOCK 4
#define BLOCK_THREADS (WAVES_PER_BLOCK * 64)
#define NW (768 * 256)   // weight elements

// ---------------- phase A: convert weights + offsets + packed pairs ----------------
__global__ __launch_bounds__(256)
void build_kernel(const int* __restrict__ batch_idx,
                  const int* __restrict__ active_idx,
                  const float* __restrict__ values,
                  const int* __restrict__ f_table,
                  const float* __restrict__ weights,
                  int* __restrict__ offsets,            // [N+1]
                  unsigned* __restrict__ pairs,         // [nnz]
                  __half* __restrict__ wh,              // [NW]
                  int nnz, int N)
{
    const int k = blockIdx.x * 256 + threadIdx.x;
    if (k < NW) wh[k] = __float2half(weights[k]);
    if (k >= nnz) return;
    const int r  = batch_idx[k];
    const int rp = (k == 0) ? -1 : batch_idx[k - 1];
    for (int row = rp + 1; row <= r; ++row) offsets[row] = k;   // lower_bound fill
    if (k == nnz - 1)
        for (int row = r + 1; row <= N; ++row) offsets[row] = nnz;
    const unsigned f = (unsigned)f_table[active_idx[k]];        // < 768
    pairs[k] = (f << 16) | (unsigned)__half_as_ushort(__float2half(values[k]));
}

// ---------------- phase B: accumulate (1 wave/row, f-sorted processing) ----------------
__global__ __launch_bounds__(BLOCK_THREADS, 8)
void gemm_kernel(const int* __restrict__ offsets,
                 const unsigned* __restrict__ pairs,
                 const __half* __restrict__ wh,
                 float* __restrict__ out, int N)
{
    const int lane = threadIdx.x & 63;
    const int row  = blockIdx.x * WAVES_PER_BLOCK + (threadIdx.x >> 6);
    if (row >= N) return;

    // Bounds via vector load (defeats s_load promotion), then broadcast.
    const int off_v = offsets[row + (lane & 1)];
    const int start = __shfl(off_v, 0);
    const int end   = __shfl(off_v, 1);
    const int cnt   = end - start;

    // One vector load covers up to 64 pairs of this row.
    unsigned praw = pairs[start + lane];                // over-read slack in ws
    praw = (lane < cnt) ? praw : 0xFFFFFFFFu;           // pads sort to the end

    // Bitonic sort of the 64 pairs across lanes (key = pair; f in high bits).
    // 21 compare-exchange stages; all-lane uniform control flow.
#pragma unroll
    for (int k = 2; k <= 64; k <<= 1) {
#pragma unroll
        for (int j = k >> 1; j >= 1; j >>= 1) {
            const unsigned other = (unsigned)__shfl_xor((int)praw, j);
            const bool up   = ((lane & k) == 0);        // ascending block?
            const bool takemin = (((lane & j) == 0) == up);
            const unsigned mn = min(praw, other), mx = max(praw, other);
            praw = takemin ? mn : mx;
        }
    }

    const int vhi  = lane >> 5;                         // 0: even nnz, 1: odd nnz
    const int vhi4 = vhi << 2;
    const __half* __restrict__ wcol = wh + ((lane & 31) << 3);  // 8 f16 cols/lane

    const __half2 zero = __float2half2_rn(0.0f);
    __half2 acc0 = zero, acc1 = zero, acc2 = zero, acc3 = zero;

    const int nb = (min(cnt, 64) + 1) >> 1;             // 2 nnz per batch

#pragma unroll 4
    for (int b = 0; b < nb; ++b) {
        const int idx = 2 * b + vhi;
        int pb = __builtin_amdgcn_ds_bpermute(vhi4 + (b << 3), (int)praw);
        pb = (idx < cnt) ? pb : 0;                      // mask pad (also keeps f in-range)
        const unsigned up = (unsigned)pb;
        const uint4 wv = *(const uint4*)((const char*)wcol + ((up >> 16) << 9));
        unsigned vvu = (up & 0xffffu) | (up << 16);     // f16(v) in both halves
        const __half2 vv = *(const __half2*)&vvu;
        const __half2* w2 = (const __half2*)&wv;
        acc0 = __hfma2(w2[0], vv, acc0);
        acc1 = __hfma2(w2[1], vv, acc1);
        acc2 = __hfma2(w2[2], vv, acc2);
        acc3 = __hfma2(w2[3], vv, acc3);
    }

    // Rare tail for rows with >64 nnz (unsorted; lo half only)
    for (int k = start + 64; k < end; ++k) {
        unsigned p = pairs[k];
        if (vhi) p = 0;
        const uint4 wv = *(const uint4*)((const char*)wcol + ((p >> 16) << 9));
        unsigned vvu = (p & 0xffffu) | (p << 16);
        const __half2 vv = *(const __half2*)&vvu;
        const __half2* w2 = (const __half2*)&wv;
        acc0 = __hfma2(w2[0], vv, acc0);
        acc1 = __hfma2(w2[1], vv, acc1);
        acc2 = __hfma2(w2[2], vv, acc2);
        acc3 = __hfma2(w2[3], vv, acc3);
    }

    // combine even/odd halves: lane l and l+32 hold the same 8 cols
    __half2 accs[4] = {acc0, acc1, acc2, acc3};
#pragma unroll
    for (int i = 0; i < 4; ++i) {
        int a = *(const int*)&accs[i];
        const int b = __shfl_xor(a, 32);
        accs[i] = __hadd2(accs[i], *(const __half2*)&b);
    }
    if (vhi == 0) {
        float4 o0, o1;
        o0.x = __low2float(accs[0]); o0.y = __high2float(accs[0]);
        o0.z = __low2float(accs[1]); o0.w = __high2float(accs[1]);
        o1.x = __low2float(accs[2]); o1.y = __high2float(accs[2]);
        o1.z = __low2float(accs[3]); o1.w = __high2float(accs[3]);
        float* orow = out + (size_t)row * OUT_COLS + ((lane & 31) << 3);
        *(float4*)orow = o0;
        *(float4*)(orow + 4) = o1;
    }
}

// ---------------- fallback (binary search, f32 weights), if ws too small ----------------
__global__ __launch_bounds__(256, 8)
void fallback_kernel(const int* __restrict__ batch_idx,
                     const int* __restrict__ active_idx,
                     const float* __restrict__ values,
                     const int* __restrict__ f_table,
                     const float* __restrict__ weights,
                     float* __restrict__ out,
                     int nnz, int N)
{
    const int wave = threadIdx.x >> 6;
    const int lane = threadIdx.x & 63;
    const int row  = blockIdx.x * 4 + wave;
    if (row >= N) return;

    int lo1 = 0, hi1 = nnz, lo2 = 0, hi2 = nnz;
    while ((lo1 < hi1) | (lo2 < hi2)) {
        if (lo1 < hi1) { int m = (lo1 + hi1) >> 1; if (batch_idx[m] < row) lo1 = m + 1; else hi1 = m; }
        if (lo2 < hi2) { int m = (lo2 + hi2) >> 1; if (batch_idx[m] < row + 1) lo2 = m + 1; else hi2 = m; }
    }
    float4 acc = make_float4(0.f, 0.f, 0.f, 0.f);
    const float* __restrict__ wcol = weights + (lane << 2);
    for (int base = lo1; base < lo2; base += 64) {
        const int c = min(lo2 - base, 64);
        float v_l = 0.f; int f_l = 0;
        if (lane < c) { const int k = base + lane; v_l = values[k]; f_l = f_table[active_idx[k]]; }
        for (int j = 0; j < c; ++j) {
            const float v = __shfl(v_l, j);
            const int   f = __shfl(f_l, j);
            const float4 w = *(const float4*)(wcol + f * OUT_COLS);
            acc.x = fmaf(v, w.x, acc.x);
            acc.y = fmaf(v, w.y, acc.y);
            acc.z = fmaf(v, w.z, acc.z);
            acc.w = fmaf(v, w.w, acc.w);
        }
    }
    *(float4*)(out + row * OUT_COLS + (lane << 2)) = acc;
}

extern "C" void kernel_launch(void* const* d_in, const int* in_sizes, int n_in,
                              void* d_out, int out_size, void* d_ws, size_t ws_size,
                              hipStream_t stream) {
    const int*   batch_idx  = (const int*)d_in[0];
    const int*   active_idx = (const int*)d_in[1];
    const float* values     = (const float*)d_in[2];
    const int*   f_table    = (const int*)d_in[3];
    const float* weights    = (const float*)d_in[4];
    float*       out        = (float*)d_out;

    const int nnz = in_sizes[0];
    const int N   = out_size / OUT_COLS;  // 16384

    // ws layout: offsets[N+1] | wh[NW] f16 | pairs[nnz] u32 | 256 B over-read slack
    const size_t off_bytes = (size_t)(N + 1) * sizeof(int);
    const size_t wh_off    = (off_bytes + 15) & ~(size_t)15;
    const size_t pairs_off = (wh_off + (size_t)NW * 2 + 15) & ~(size_t)15;
    const size_t need      = pairs_off + (size_t)nnz * sizeof(unsigned) + 256;

    const int grid_rows = (N + WAVES_PER_BLOCK - 1) / WAVES_PER_BLOCK;

    if (ws_size >= need) {
        int*      offsets = (int*)d_ws;
        __half*   wh      = (__half*)((char*)d_ws + wh_off);
        unsigned* pairs   = (unsigned*)((char*)d_ws + pairs_off);

        const int work = (nnz > NW) ? nnz : NW;
        build_kernel<<<(work + 255) / 256, 256, 0, stream>>>(
            batch_idx, active_idx, values, f_table, weights,
            offsets, pairs, wh, nnz, N);
        gemm_kernel<<<grid_rows, BLOCK_THREADS, 0, stream>>>(offsets, pairs, wh, out, N);
    } else {
        fallback_kernel<<<grid_rows, 256, 0, stream>>>(
            batch_idx, active_idx, values, f_table, weights, out, nnz, N);
    }
}